// Round 7
// baseline (127.541 us; speedup 1.0000x reference)
//
#include <hip/hip_runtime.h>
#include <math.h>

#define NN 50000
#define FD 128
#define HDIM 256
#define NE 800000
#define NBR_CAP 512
#define M_CAP 8192
#define TT 7
#define GRID 144          // multiple of 16 (barrier tree: 9 arrivals per line)
#define TPB 256
#define SBLK 8            // stepper blocks
#define PPB 8             // p-values per block: 144*8 = 1152
#define ECHUNK 2048
#define GTH (GRID * TPB)

// ws offsets. CTRL region zeroed by the memset node each call.
#define O_BARC    0        // 16 counters x 64B stride -> 1024
#define O_GO      1024
#define O_NBRCNT  1088
#define O_MCNT    1152
#define O_FLAGS   1216     // TT*SBLK u32 -> 1440
#define O_GACC    1536     // 1024 f -> 5632
#define O_HGLOB   5632     // TT*256 f -> 12800
#define CTRL_BYTES 12800
#define O_DEG     12800    // NN f -> 212800 (zeroed in-kernel, scan1)
#define O_BITMAP  212800   // 1568 u32 (zeroed in-kernel, scan1)
#define O_NBRNODE 219072   // NBR_CAP i
#define O_NBRW    221120   // NBR_CAP f
#define O_MS      223168   // M_CAP i
#define O_MD      255936   // M_CAP i
#define O_MW      288704   // M_CAP f

#define SPIN_CAP 100000000

__device__ __forceinline__ float sigm(float v) { return 1.f / (1.f + expf(-v)); }
__device__ __forceinline__ float dis_of(float dg) {
    return dg > 0.f ? rsqrtf(fmaxf(dg, 1e-20f)) : 0.f;
}
// System-scope ops execute at the LLC: always fresh (bypass L1 + per-XCD L2),
// and concurrent readers don't serialize (unlike RMW polling).
__device__ __forceinline__ float slf(const float* p) {
    return __hip_atomic_load(p, __ATOMIC_RELAXED, __HIP_MEMORY_SCOPE_SYSTEM);
}
__device__ __forceinline__ int sli(const int* p) {
    return __hip_atomic_load(p, __ATOMIC_RELAXED, __HIP_MEMORY_SCOPE_SYSTEM);
}
__device__ __forceinline__ unsigned slu(const unsigned* p) {
    return __hip_atomic_load(p, __ATOMIC_RELAXED, __HIP_MEMORY_SCOPE_SYSTEM);
}
__device__ __forceinline__ void ssf(float* p, float v) {
    __hip_atomic_store(p, v, __ATOMIC_RELAXED, __HIP_MEMORY_SCOPE_SYSTEM);
}
__device__ __forceinline__ void ssi(int* p, int v) {
    __hip_atomic_store(p, v, __ATOMIC_RELAXED, __HIP_MEMORY_SCOPE_SYSTEM);
}
__device__ __forceinline__ void ssu(unsigned* p, unsigned v) {
    __hip_atomic_store(p, v, __ATOMIC_RELAXED, __HIP_MEMORY_SCOPE_SYSTEM);
}

// Tree barrier: arrivals spread over 16 padded lines (9 RMWs each, parallel
// across LLC channels); root (block 0) detects and release-stores go=gen;
// everyone polls go with a system acquire load.
__device__ __forceinline__ void megabar(char* ws, unsigned gen, int bid, bool poll_go) {
    unsigned* barc = (unsigned*)(ws + O_BARC);
    unsigned* go   = (unsigned*)(ws + O_GO);
    __syncthreads();
    if (threadIdx.x == 0) {
        __hip_atomic_fetch_add(&barc[(bid & 15) * 16], 1u, __ATOMIC_RELEASE,
                               __HIP_MEMORY_SCOPE_SYSTEM);
        if (bid == 0) {
            for (int r = 0; r < 16; ++r) {
                int sp = 0;
                while (slu(&barc[r * 16]) < gen * (GRID / 16)) {
                    __builtin_amdgcn_s_sleep(2);
                    if (++sp > SPIN_CAP) break;
                }
            }
            __hip_atomic_store(go, gen, __ATOMIC_RELEASE, __HIP_MEMORY_SCOPE_SYSTEM);
        }
        if (poll_go) {
            int sp = 0;
            while (__hip_atomic_load(go, __ATOMIC_ACQUIRE, __HIP_MEMORY_SCOPE_SYSTEM) < gen) {
                __builtin_amdgcn_s_sleep(2);
                if (++sp > SPIN_CAP) break;
            }
        }
    }
    __syncthreads();
}

__global__ __launch_bounds__(TPB, 1) void k_mega(
    const float* __restrict__ x, const int* __restrict__ ei, const float* __restrict__ ew,
    const float* __restrict__ h, const float* __restrict__ c,
    const float* __restrict__ theta_x, const float* __restrict__ bias_x,
    const float* __restrict__ theta_h, const float* __restrict__ bias_h,
    const float* __restrict__ w_c, const float* __restrict__ b_gate,
    const float* __restrict__ w_ih, const float* __restrict__ w_hh,
    const float* __restrict__ b_ih, const float* __restrict__ b_hh,
    const float* __restrict__ w_out, const float* __restrict__ b_out,
    float* __restrict__ out, char* __restrict__ ws) {

    float*    deg    = (float*)(ws + O_DEG);
    unsigned* bitmap = (unsigned*)(ws + O_BITMAP);
    int*      nbrCnt = (int*)(ws + O_NBRCNT);
    int*      mCnt   = (int*)(ws + O_MCNT);
    unsigned* flags  = (unsigned*)(ws + O_FLAGS);
    float*    gacc   = (float*)(ws + O_GACC);
    float*    hglob  = (float*)(ws + O_HGLOB);
    int*      nbrNode= (int*)(ws + O_NBRNODE);
    float*    nbrW   = (float*)(ws + O_NBRW);
    int*      mS     = (int*)(ws + O_MS);
    int*      mD     = (int*)(ws + O_MD);
    float*    mW     = (float*)(ws + O_MW);

    __shared__ int   sNode[NBR_CAP];
    __shared__ float sWl[NBR_CAP];
    __shared__ float cf1[ECHUNK], cf2[ECHUNK];
    __shared__ int   sS[ECHUNK];
    __shared__ float red1[TPB], red2[TPB];
    __shared__ float tslice[PPB];
    __shared__ __align__(16) float sh[HDIM];
    __shared__ float sc[HDIM];
    __shared__ float sdot[128];
    __shared__ float swsum[4];
    __shared__ int   sCnt, sMcnt;

    const int tid = threadIdx.x, bid = blockIdx.x;
    const int gidx = bid * TPB + tid;
    const bool stepper = bid < SBLK;

    // ---- stepper w_hh preload into VGPRs (overlaps the scans) ----
    // 8 blocks x 256 thr; 2 threads per gate-row; 128 floats (32 float4) each.
    const int rl2 = tid >> 1, half = tid & 1;
    const int grow = (rl2 >> 5) * HDIM + bid * 32 + (rl2 & 31);
    float4 wreg[32];
    float wih_r = 0.f, br = 0.f, wout_r = 0.f;
    if (stepper) {
        const float* wrow = w_hh + (size_t)grow * HDIM + half * 128;
        #pragma unroll
        for (int k = 0; k < 32; ++k) wreg[k] = *(const float4*)&wrow[k * 4];
        wih_r = w_ih[grow];
        br    = b_ih[grow] + b_hh[grow];
        wout_r = w_out[tid];
    }
    const float bo = b_out[0];

    // ================ scan1: zero deg/bitmap; collect nbr(0) ================
    for (int i = gidx; i < NN; i += GTH) ssf(&deg[i], 0.f);
    for (int i = gidx; i < 1568; i += GTH) ssu(&bitmap[i], 0u);
    for (int e0 = gidx * 4; e0 < NE; e0 += GTH * 4) {
        int4 d4 = *(const int4*)&ei[NE + e0];
        float4 w4 = *(const float4*)&ew[e0];
        int dd[4] = {d4.x, d4.y, d4.z, d4.w};
        float wv[4] = {w4.x, w4.y, w4.z, w4.w};
        #pragma unroll
        for (int k = 0; k < 4; ++k) {
            if (dd[k] == 0 && wv[k] != 0.f) {
                int s = ei[e0 + k];
                if (s != 0) {
                    int slot = atomicAdd(nbrCnt, 1);
                    if (slot < NBR_CAP) { ssi(&nbrNode[slot], s); ssf(&nbrW[slot], wv[k]); }
                }
            }
        }
    }
    megabar(ws, 1, bid, true);

    // nbr list -> LDS (every block)
    if (tid == 0) sCnt = min(sli(nbrCnt), NBR_CAP);
    __syncthreads();
    const int ncnt = sCnt;
    for (int i = tid; i < ncnt; i += TPB) { sNode[i] = sli(&nbrNode[i]); sWl[i] = slf(&nbrW[i]); }
    if (bid == 0 && tid == 0) atomicOr(&bitmap[0], 1u);   // deg[0] needed
    __syncthreads();

    // ================ scan2: match edges into 2-hop set ================
    for (int e0 = gidx * 4; e0 < NE; e0 += GTH * 4) {
        int4 s4 = *(const int4*)&ei[e0];
        int4 d4 = *(const int4*)&ei[NE + e0];
        float4 w4 = *(const float4*)&ew[e0];
        int ss[4] = {s4.x, s4.y, s4.z, s4.w};
        int dd[4] = {d4.x, d4.y, d4.z, d4.w};
        float wv[4] = {w4.x, w4.y, w4.z, w4.w};
        bool m[4];
        #pragma unroll
        for (int k = 0; k < 4; ++k) m[k] = (dd[k] == 0);
        for (int j = 0; j < ncnt; ++j) {
            int nv = sNode[j];
            #pragma unroll
            for (int k = 0; k < 4; ++k) m[k] |= (dd[k] == nv);
        }
        #pragma unroll
        for (int k = 0; k < 4; ++k) {
            int s = ss[k], d = dd[k];
            float w = wv[k];
            if (s == d || w == 0.f || !m[k]) continue;
            int slot = atomicAdd(mCnt, 1);
            if (slot < M_CAP) { ssi(&mS[slot], s); ssi(&mD[slot], d); ssf(&mW[slot], w); }
            atomicOr(&bitmap[s >> 5], 1u << (s & 31));
            atomicOr(&bitmap[d >> 5], 1u << (d & 31));
        }
    }
    megabar(ws, 2, bid, true);

    // ================ scan3: deg for bitmap-marked srcs ================
    for (int e0 = gidx * 4; e0 < NE; e0 += GTH * 4) {
        int4 s4 = *(const int4*)&ei[e0];
        int4 d4 = *(const int4*)&ei[NE + e0];
        float4 w4 = *(const float4*)&ew[e0];
        int ss[4] = {s4.x, s4.y, s4.z, s4.w};
        int dd[4] = {d4.x, d4.y, d4.z, d4.w};
        float wv[4] = {w4.x, w4.y, w4.z, w4.w};
        #pragma unroll
        for (int k = 0; k < 4; ++k) {
            int s = ss[k];
            if (s == dd[k] || wv[k] == 0.f) continue;
            if (bitmap[s >> 5] & (1u << (s & 31)))   // cached: only atomics wrote it
                atomicAdd(&deg[s], wv[k]);
        }
    }
    megabar(ws, 3, bid, true);

    // ================ graph: block-local T-slice (8 p) + gemv ================
    if (tid == 0) sMcnt = min(sli(mCnt), M_CAP);
    __syncthreads();
    const int mcnt = sMcnt;
    const float dis0 = dis_of(slf(&deg[0]));

    const int pidx = tid & 7, eg = tid >> 3;             // 32 edge-groups x 8 p
    const int p = bid * PPB + pidx;
    const bool isx = p < 3 * FD;
    const int q = isx ? p : p - 3 * FD;
    const int korder = isx ? (q / FD) : (q / HDIM);
    const int f = isx ? (q % FD) : (q % HDIM);
    const float* fbase = isx ? (x + f) : (h + f);
    const int fstride = isx ? FD : HDIM;
    const float f0 = fbase[0];

    float a1 = 0.f, a2 = 0.f;
    for (int c0i = 0; c0i < mcnt; c0i += ECHUNK) {
        int clen = min(ECHUNK, mcnt - c0i);
        for (int i = tid; i < clen; i += TPB) {          // per-edge coefs
            int sI = sli(&mS[c0i + i]), dI = sli(&mD[c0i + i]);
            float w = slf(&mW[c0i + i]);
            float disd = dis_of(slf(&deg[dI]));
            float wn = dis_of(slf(&deg[sI])) * w * disd;
            float Wd = 0.f;
            for (int j = 0; j < ncnt; ++j) Wd += (sNode[j] == dI) ? sWl[j] : 0.f;
            cf1[i] = (dI == 0) ? wn : 0.f;
            cf2[i] = wn * (dis0 * disd * Wd);
            sS[i] = sI;
        }
        __syncthreads();
        for (int i = eg; i < clen; i += 32) {            // gather-reduce
            float v = fbase[(size_t)sS[i] * fstride];
            a1 += cf1[i] * v;
            a2 += cf2[i] * v;
        }
        __syncthreads();
    }
    red1[tid] = a1; red2[tid] = a2;
    __syncthreads();
    if (tid < PPB) {
        float A1 = 0.f, A2 = 0.f;
        #pragma unroll
        for (int e = 0; e < 32; ++e) { A1 += red1[tid + 8 * e]; A2 += red2[tid + 8 * e]; }
        tslice[tid] = (korder == 0) ? f0 : ((korder == 1) ? -A1 : 2.f * A2 - f0);
    }
    __syncthreads();

    {   // gemv over this block's 8 p-rows; thread owns output o = tid
        float g0 = 0.f, g1 = 0.f, g2v = 0.f, g3 = 0.f;
        #pragma unroll
        for (int pp = 0; pp < PPB; ++pp) {
            int p2 = bid * PPB + pp;
            float tv = tslice[pp];
            bool ix = p2 < 3 * FD;
            int qq = ix ? p2 : p2 - 3 * FD;
            const float* bb = ix ? (theta_x + (size_t)qq * HDIM)
                                 : (theta_h + (size_t)qq * HDIM);
            size_t gs = ix ? (size_t)(3 * FD) * HDIM : (size_t)(3 * HDIM) * HDIM;
            g0  += tv * bb[tid];
            g1  += tv * bb[gs + tid];
            g2v += tv * bb[2 * gs + tid];
            g3  += tv * bb[3 * gs + tid];
        }
        atomicAdd(&gacc[0 * HDIM + tid], g0);
        atomicAdd(&gacc[1 * HDIM + tid], g1);
        atomicAdd(&gacc[2 * HDIM + tid], g2v);
        atomicAdd(&gacc[3 * HDIM + tid], g3);
    }

    // B4: non-steppers arrive and exit; steppers wait for go.
    __syncthreads();
    if (!stepper) {
        if (tid == 0)
            __hip_atomic_fetch_add((unsigned*)(ws + O_BARC) + (bid & 15) * 16, 1u,
                                   __ATOMIC_RELEASE, __HIP_MEMORY_SCOPE_SYSTEM);
        return;
    }
    if (tid == 0) {
        unsigned* barc = (unsigned*)(ws + O_BARC);
        unsigned* go   = (unsigned*)(ws + O_GO);
        __hip_atomic_fetch_add(&barc[(bid & 15) * 16], 1u, __ATOMIC_RELEASE,
                               __HIP_MEMORY_SCOPE_SYSTEM);
        if (bid == 0) {
            for (int r = 0; r < 16; ++r) {
                int sp = 0;
                while (slu(&barc[r * 16]) < 4u * (GRID / 16)) {
                    __builtin_amdgcn_s_sleep(2);
                    if (++sp > SPIN_CAP) break;
                }
            }
            __hip_atomic_store(go, 4u, __ATOMIC_RELEASE, __HIP_MEMORY_SCOPE_SYSTEM);
        }
        int sp = 0;
        while (__hip_atomic_load(go, __ATOMIC_ACQUIRE, __HIP_MEMORY_SCOPE_SYSTEM) < 4u) {
            __builtin_amdgcn_s_sleep(2);
            if (++sp > SPIN_CAP) break;
        }
    }
    __syncthreads();

    // ================ gates (redundant per stepper block) ================
    {
        const int o = tid;
        float g0 = slf(&gacc[0 * HDIM + o]) + bias_x[0 * HDIM + o] + bias_h[0 * HDIM + o];
        float g1 = slf(&gacc[1 * HDIM + o]) + bias_x[1 * HDIM + o] + bias_h[1 * HDIM + o];
        float g2 = slf(&gacc[2 * HDIM + o]) + bias_x[2 * HDIM + o] + bias_h[2 * HDIM + o];
        float g3 = slf(&gacc[3 * HDIM + o]) + bias_x[3 * HDIM + o] + bias_h[3 * HDIM + o];
        float c0 = c[o];
        float I  = sigm(g0 + w_c[0 * HDIM + o] * c0 + b_gate[0 * HDIM + o]);
        float Fg = sigm(g1 + w_c[1 * HDIM + o] * c0 + b_gate[1 * HDIM + o]);
        float Cn = Fg * c0 + I * tanhf(g2 + b_gate[2 * HDIM + o]);
        float O  = sigm(g3 + w_c[2 * HDIM + o] * Cn + b_gate[3 * HDIM + o]);
        sh[o] = O * tanhf(Cn);
        sc[o] = Cn;
    }
    __syncthreads();
    float creg = (tid < 32) ? sc[bid * 32 + tid] : 0.f;
    float sinp = x[FD - 1];

    // ================ 7 LSTM steps (flag-signaled among 8 blocks) ================
    for (int t = 0; t < TT; ++t) {
        // dot: row rl2 (128 rows/block), 2 threads/row
        float acc = 0.f;
        const float* shh = &sh[half * 128];
        #pragma unroll
        for (int k = 0; k < 32; ++k) {
            float4 hv = *(const float4*)&shh[k * 4];
            acc += hv.x * wreg[k].x + hv.y * wreg[k].y + hv.z * wreg[k].z + hv.w * wreg[k].w;
        }
        acc += __shfl_xor(acc, 1);
        if (half == 0) sdot[rl2] = acc + sinp * wih_r + br;
        __syncthreads();                       // S1: sh reads done, sdot ready
        if (tid < 32) {
            float iv = sdot[tid], fv = sdot[32 + tid], gv = sdot[64 + tid], ov = sdot[96 + tid];
            float cn = sigm(fv) * creg + sigm(iv) * tanhf(gv);
            float hn = sigm(ov) * tanhf(cn);
            creg = cn;
            ssf(&hglob[t * HDIM + bid * 32 + tid], hn);
        }
        if (tid == 0)   // same wave as the 32 h stores: release drains them first
            __hip_atomic_store(&flags[t * SBLK + bid], 1u, __ATOMIC_RELEASE,
                               __HIP_MEMORY_SCOPE_SYSTEM);
        if (tid < 64) { // wave 0: poll 8 flags, then pull the full h into LDS
            if (tid < SBLK) {
                int sp = 0;
                while (__hip_atomic_load(&flags[t * SBLK + tid], __ATOMIC_ACQUIRE,
                                         __HIP_MEMORY_SCOPE_SYSTEM) == 0u) {
                    __builtin_amdgcn_s_sleep(1);
                    if (++sp > SPIN_CAP) break;
                }
            }
            #pragma unroll
            for (int j = 0; j < 4; ++j)
                sh[tid * 4 + j] = slf(&hglob[t * HDIM + tid * 4 + j]);
        }
        __syncthreads();                       // S2: new h visible to all
        float pw = wout_r * sh[tid];
        pw += __shfl_down(pw, 32);
        pw += __shfl_down(pw, 16);
        pw += __shfl_down(pw, 8);
        pw += __shfl_down(pw, 4);
        pw += __shfl_down(pw, 2);
        pw += __shfl_down(pw, 1);
        if ((tid & 63) == 0) swsum[tid >> 6] = pw;
        __syncthreads();                       // S3: swsum ready
        float sval = swsum[0] + swsum[1] + swsum[2] + swsum[3] + bo;
        sinp = sval;
        if (bid == 0 && tid == 0) out[t] = sval;
    }
}

extern "C" void kernel_launch(void* const* d_in, const int* in_sizes, int n_in,
                              void* d_out, int out_size, void* d_ws, size_t ws_size,
                              hipStream_t stream) {
    const float* x       = (const float*)d_in[0];
    const int*   ei      = (const int*)d_in[1];
    const float* ew      = (const float*)d_in[2];
    const float* h       = (const float*)d_in[3];
    const float* c       = (const float*)d_in[4];
    const float* theta_x = (const float*)d_in[5];
    const float* bias_x  = (const float*)d_in[6];
    const float* theta_h = (const float*)d_in[7];
    const float* bias_h  = (const float*)d_in[8];
    const float* w_c     = (const float*)d_in[9];
    const float* b_gate  = (const float*)d_in[10];
    const float* w_ih    = (const float*)d_in[11];
    const float* w_hh    = (const float*)d_in[12];
    const float* b_ih    = (const float*)d_in[13];
    const float* b_hh    = (const float*)d_in[14];
    const float* w_out   = (const float*)d_in[15];
    const float* b_out   = (const float*)d_in[16];

    hipMemsetAsync(d_ws, 0, CTRL_BYTES, stream);
    k_mega<<<GRID, TPB, 0, stream>>>(x, ei, ew, h, c, theta_x, bias_x, theta_h, bias_h,
                                     w_c, b_gate, w_ih, w_hh, b_ih, b_hh, w_out, b_out,
                                     (float*)d_out, (char*)d_ws);
}

// Round 8
// 91.292 us; speedup vs baseline: 1.3971x; 1.3971x over previous
//
#include <hip/hip_runtime.h>
#include <math.h>

#define NN 50000
#define FD 128
#define HDIM 256
#define NE 800000
#define NBR_CAP 512
#define M_CAP 8192
#define TT 7
#define GRID 144          // 144*8 = 1152 p-values exactly
#define TPB 256
#define SBLK 32           // stepper blocks (first 32)
#define PPB 8             // p-values per block
#define ECHUNK 2048
#define GTH (GRID * TPB)

// ws offsets. CTRL region zeroed by the memset node each call.
#define O_BARC    0        // barrier counter (monotonic across 4 gens)
#define O_NBRCNT  64
#define O_MCNT    128
#define O_HSYNC   256      // TT*HDIM u64 (tag<<32 | h bits) -> 14592
#define O_GACC    14592    // 1024 f -> 18688
#define CTRL_BYTES 18688
#define O_DEG     18688    // NN f (zeroed in-kernel scan1)
#define O_BITMAP  218688   // 1568 u32 (zeroed in-kernel scan1)
#define O_NBRNODE 224960   // NBR_CAP i
#define O_NBRW    227008   // NBR_CAP f
#define O_MS      229056   // M_CAP i
#define O_MD      261824   // M_CAP i
#define O_MW      294592   // M_CAP f -> 327360

#define SPIN_CAP 50000000

__device__ __forceinline__ float sigm(float v) { return 1.f / (1.f + expf(-v)); }
__device__ __forceinline__ float dis_of(float dg) {
    return dg > 0.f ? rsqrtf(fmaxf(dg, 1e-20f)) : 0.f;
}
// System-scope ops execute at the LLC: always fresh (bypass L1 + per-XCD L2);
// concurrent LOADS of one line are served in parallel (unlike RMW polling).
__device__ __forceinline__ float slf(const float* p) {
    return __hip_atomic_load(p, __ATOMIC_RELAXED, __HIP_MEMORY_SCOPE_SYSTEM);
}
__device__ __forceinline__ int sli(const int* p) {
    return __hip_atomic_load(p, __ATOMIC_RELAXED, __HIP_MEMORY_SCOPE_SYSTEM);
}
__device__ __forceinline__ void ssf(float* p, float v) {
    __hip_atomic_store(p, v, __ATOMIC_RELAXED, __HIP_MEMORY_SCOPE_SYSTEM);
}
__device__ __forceinline__ void ssi(int* p, int v) {
    __hip_atomic_store(p, v, __ATOMIC_RELAXED, __HIP_MEMORY_SCOPE_SYSTEM);
}
__device__ __forceinline__ void ssu(unsigned* p, unsigned v) {
    __hip_atomic_store(p, v, __ATOMIC_RELAXED, __HIP_MEMORY_SCOPE_SYSTEM);
}

// Single-counter barrier: RMW arrival (release), system-scope LOAD poll.
__device__ __forceinline__ void bar(unsigned* ctr, unsigned tgt) {
    __syncthreads();
    if (threadIdx.x == 0) {
        __hip_atomic_fetch_add(ctr, 1u, __ATOMIC_ACQ_REL, __HIP_MEMORY_SCOPE_SYSTEM);
        int sp = 0;
        while (__hip_atomic_load(ctr, __ATOMIC_ACQUIRE, __HIP_MEMORY_SCOPE_SYSTEM) < tgt) {
            __builtin_amdgcn_s_sleep(2);
            if (++sp > SPIN_CAP) break;
        }
    }
    __syncthreads();
}

__global__ __launch_bounds__(TPB, 1) void k_mega(
    const float* __restrict__ x, const int* __restrict__ ei, const float* __restrict__ ew,
    const float* __restrict__ h, const float* __restrict__ c,
    const float* __restrict__ theta_x, const float* __restrict__ bias_x,
    const float* __restrict__ theta_h, const float* __restrict__ bias_h,
    const float* __restrict__ w_c, const float* __restrict__ b_gate,
    const float* __restrict__ w_ih, const float* __restrict__ w_hh,
    const float* __restrict__ b_ih, const float* __restrict__ b_hh,
    const float* __restrict__ w_out, const float* __restrict__ b_out,
    float* __restrict__ out, char* __restrict__ ws) {

    unsigned*           barc   = (unsigned*)(ws + O_BARC);
    int*                nbrCnt = (int*)(ws + O_NBRCNT);
    int*                mCnt   = (int*)(ws + O_MCNT);
    unsigned long long* hsync  = (unsigned long long*)(ws + O_HSYNC);
    float*              gacc   = (float*)(ws + O_GACC);
    float*              deg    = (float*)(ws + O_DEG);
    unsigned*           bitmap = (unsigned*)(ws + O_BITMAP);
    int*                nbrNode= (int*)(ws + O_NBRNODE);
    float*              nbrW   = (float*)(ws + O_NBRW);
    int*                mS     = (int*)(ws + O_MS);
    int*                mD     = (int*)(ws + O_MD);
    float*              mW     = (float*)(ws + O_MW);

    __shared__ int   sNode[NBR_CAP];
    __shared__ float sWl[NBR_CAP];
    __shared__ float cf1[ECHUNK], cf2[ECHUNK];
    __shared__ int   sS[ECHUNK];
    __shared__ float red1[TPB], red2[TPB];
    __shared__ float tslice[PPB];
    __shared__ __align__(16) float sh[HDIM];
    __shared__ float sc[HDIM];
    __shared__ float sdot[SBLK];
    __shared__ float swsum[4];
    __shared__ int   sCnt, sMcnt;

    const int tid = threadIdx.x, bid = blockIdx.x;
    const int gidx = bid * TPB + tid;
    const bool stepper = bid < SBLK;

    // ---- stepper preloads (overlap scan1's HBM work). wreg[8] = 32 VGPRs: the
    // round-5/6 proven no-spill layout (32 gate rows/block, 8 threads/row). ----
    const int rl = tid >> 3, seg = tid & 7;
    const int grow = (rl >> 3) * HDIM + bid * 8 + (rl & 7);
    float4 wreg[8];
    float wih_r = 0.f, br = 0.f, wout_r = 0.f;
    if (stepper) {
        #pragma unroll
        for (int k = 0; k < 8; ++k)
            wreg[k] = *(const float4*)&w_hh[(size_t)grow * HDIM + seg * 32 + k * 4];
        wih_r = w_ih[grow];
        br    = b_ih[grow] + b_hh[grow];
        wout_r = w_out[tid];                     // every stepper thread: its h-dim's weight
    }
    const float bo = b_out[0];

    // ================ scan1: zero deg/bitmap; collect nbr(0) ================
    for (int i = gidx; i < NN; i += GTH) ssf(&deg[i], 0.f);
    for (int i = gidx; i < 1568; i += GTH) ssu(&bitmap[i], 0u);
    for (int e0 = gidx * 4; e0 < NE; e0 += GTH * 4) {
        int4 d4 = *(const int4*)&ei[NE + e0];
        float4 w4 = *(const float4*)&ew[e0];
        int dd[4] = {d4.x, d4.y, d4.z, d4.w};
        float wv[4] = {w4.x, w4.y, w4.z, w4.w};
        #pragma unroll
        for (int k = 0; k < 4; ++k) {
            if (dd[k] == 0 && wv[k] != 0.f) {
                int s = ei[e0 + k];
                if (s != 0) {
                    int slot = atomicAdd(nbrCnt, 1);
                    if (slot < NBR_CAP) { ssi(&nbrNode[slot], s); ssf(&nbrW[slot], wv[k]); }
                }
            }
        }
    }
    bar(barc, 1u * GRID);

    // nbr list -> LDS (every block)
    if (tid == 0) sCnt = min(sli(nbrCnt), NBR_CAP);
    __syncthreads();
    const int ncnt = sCnt;
    for (int i = tid; i < ncnt; i += TPB) { sNode[i] = sli(&nbrNode[i]); sWl[i] = slf(&nbrW[i]); }
    if (bid == 0 && tid == 0) atomicOr(&bitmap[0], 1u);   // deg[0] needed
    __syncthreads();

    // ================ scan2: match edges into 2-hop set ================
    for (int e0 = gidx * 4; e0 < NE; e0 += GTH * 4) {
        int4 s4 = *(const int4*)&ei[e0];
        int4 d4 = *(const int4*)&ei[NE + e0];
        float4 w4 = *(const float4*)&ew[e0];
        int ss[4] = {s4.x, s4.y, s4.z, s4.w};
        int dd[4] = {d4.x, d4.y, d4.z, d4.w};
        float wv[4] = {w4.x, w4.y, w4.z, w4.w};
        bool m[4];
        #pragma unroll
        for (int k = 0; k < 4; ++k) m[k] = (dd[k] == 0);
        for (int j = 0; j < ncnt; ++j) {
            int nv = sNode[j];
            #pragma unroll
            for (int k = 0; k < 4; ++k) m[k] |= (dd[k] == nv);
        }
        #pragma unroll
        for (int k = 0; k < 4; ++k) {
            int s = ss[k], d = dd[k];
            float w = wv[k];
            if (s == d || w == 0.f || !m[k]) continue;
            int slot = atomicAdd(mCnt, 1);
            if (slot < M_CAP) { ssi(&mS[slot], s); ssi(&mD[slot], d); ssf(&mW[slot], w); }
            atomicOr(&bitmap[s >> 5], 1u << (s & 31));
            atomicOr(&bitmap[d >> 5], 1u << (d & 31));
        }
    }
    bar(barc, 2u * GRID);

    // ================ scan3: deg for bitmap-marked srcs ================
    for (int e0 = gidx * 4; e0 < NE; e0 += GTH * 4) {
        int4 s4 = *(const int4*)&ei[e0];
        int4 d4 = *(const int4*)&ei[NE + e0];
        float4 w4 = *(const float4*)&ew[e0];
        int ss[4] = {s4.x, s4.y, s4.z, s4.w};
        int dd[4] = {d4.x, d4.y, d4.z, d4.w};
        float wv[4] = {w4.x, w4.y, w4.z, w4.w};
        #pragma unroll
        for (int k = 0; k < 4; ++k) {
            int s = ss[k];
            if (s == dd[k] || wv[k] == 0.f) continue;
            if (bitmap[s >> 5] & (1u << (s & 31)))
                atomicAdd(&deg[s], wv[k]);
        }
    }
    bar(barc, 3u * GRID);

    // ================ graph: block-local T-slice (8 p) + gemv (32 rows) ================
    if (tid == 0) sMcnt = min(sli(mCnt), M_CAP);
    __syncthreads();
    const int mcnt = sMcnt;
    const float dis0 = dis_of(slf(&deg[0]));

    const int pidx = tid & 7, eg = tid >> 3;             // 32 edge-groups x 8 p
    const int p = bid * PPB + pidx;
    const bool isx = p < 3 * FD;
    const int q = isx ? p : p - 3 * FD;
    const int korder = isx ? (q / FD) : (q / HDIM);
    const int f = isx ? (q % FD) : (q % HDIM);
    const float* fbase = isx ? (x + f) : (h + f);
    const int fstride = isx ? FD : HDIM;
    const float f0 = fbase[0];

    float a1 = 0.f, a2 = 0.f;
    for (int c0i = 0; c0i < mcnt; c0i += ECHUNK) {
        int clen = min(ECHUNK, mcnt - c0i);
        for (int i = tid; i < clen; i += TPB) {          // per-edge coefs
            int sI = sli(&mS[c0i + i]), dI = sli(&mD[c0i + i]);
            float w = slf(&mW[c0i + i]);
            float disd = dis_of(slf(&deg[dI]));
            float wn = dis_of(slf(&deg[sI])) * w * disd;
            float Wd = 0.f;
            for (int j = 0; j < ncnt; ++j) Wd += (sNode[j] == dI) ? sWl[j] : 0.f;
            cf1[i] = (dI == 0) ? wn : 0.f;
            cf2[i] = wn * (dis0 * disd * Wd);
            sS[i] = sI;
        }
        __syncthreads();
        for (int i = eg; i < clen; i += 32) {            // gather-reduce
            float v = fbase[(size_t)sS[i] * fstride];
            a1 += cf1[i] * v;
            a2 += cf2[i] * v;
        }
        __syncthreads();
    }
    red1[tid] = a1; red2[tid] = a2;
    __syncthreads();
    if (tid < PPB) {
        float A1 = 0.f, A2 = 0.f;
        #pragma unroll
        for (int e = 0; e < 32; ++e) { A1 += red1[tid + 8 * e]; A2 += red2[tid + 8 * e]; }
        tslice[tid] = (korder == 0) ? f0 : ((korder == 1) ? -A1 : 2.f * A2 - f0);
    }
    __syncthreads();

    {   // gemv over this block's 8 p-rows; thread owns output o = tid
        float g0 = 0.f, g1 = 0.f, g2v = 0.f, g3 = 0.f;
        #pragma unroll
        for (int pp = 0; pp < PPB; ++pp) {
            int p2 = bid * PPB + pp;
            float tv = tslice[pp];
            bool ix = p2 < 3 * FD;
            int qq = ix ? p2 : p2 - 3 * FD;
            const float* bb = ix ? (theta_x + (size_t)qq * HDIM)
                                 : (theta_h + (size_t)qq * HDIM);
            size_t gs = ix ? (size_t)(3 * FD) * HDIM : (size_t)(3 * HDIM) * HDIM;
            g0  += tv * bb[tid];
            g1  += tv * bb[gs + tid];
            g2v += tv * bb[2 * gs + tid];
            g3  += tv * bb[3 * gs + tid];
        }
        atomicAdd(&gacc[0 * HDIM + tid], g0);
        atomicAdd(&gacc[1 * HDIM + tid], g1);
        atomicAdd(&gacc[2 * HDIM + tid], g2v);
        atomicAdd(&gacc[3 * HDIM + tid], g3);
    }

    // B4: non-steppers arrive and exit; steppers wait for all arrivals.
    __syncthreads();
    if (!stepper) {
        if (tid == 0)
            __hip_atomic_fetch_add(barc, 1u, __ATOMIC_ACQ_REL, __HIP_MEMORY_SCOPE_SYSTEM);
        return;
    }
    bar(barc, 4u * GRID);

    // ================ gates (redundant per stepper block) ================
    {
        const int o = tid;
        float g0 = slf(&gacc[0 * HDIM + o]) + bias_x[0 * HDIM + o] + bias_h[0 * HDIM + o];
        float g1 = slf(&gacc[1 * HDIM + o]) + bias_x[1 * HDIM + o] + bias_h[1 * HDIM + o];
        float g2 = slf(&gacc[2 * HDIM + o]) + bias_x[2 * HDIM + o] + bias_h[2 * HDIM + o];
        float g3 = slf(&gacc[3 * HDIM + o]) + bias_x[3 * HDIM + o] + bias_h[3 * HDIM + o];
        float c0 = c[o];
        float I  = sigm(g0 + w_c[0 * HDIM + o] * c0 + b_gate[0 * HDIM + o]);
        float Fg = sigm(g1 + w_c[1 * HDIM + o] * c0 + b_gate[1 * HDIM + o]);
        float Cn = Fg * c0 + I * tanhf(g2 + b_gate[2 * HDIM + o]);
        float O  = sigm(g3 + w_c[2 * HDIM + o] * Cn + b_gate[3 * HDIM + o]);
        sh[o] = O * tanhf(Cn);
        sc[o] = Cn;
    }
    __syncthreads();
    float creg = (tid < 8) ? sc[bid * 8 + tid] : 0.f;
    float sinp = x[FD - 1];

    // ====== 7 LSTM steps: one tagged u64 store per h-value, consumers poll it ======
    for (int t = 0; t < TT; ++t) {
        float acc = 0.f;
        const float* shh = &sh[seg * 32];
        #pragma unroll
        for (int k = 0; k < 8; ++k) {
            float4 hv = *(const float4*)&shh[k * 4];
            acc += hv.x * wreg[k].x + hv.y * wreg[k].y + hv.z * wreg[k].z + hv.w * wreg[k].w;
        }
        acc += __shfl_down(acc, 4);
        acc += __shfl_down(acc, 2);
        acc += __shfl_down(acc, 1);
        if (seg == 0) sdot[rl] = acc + sinp * wih_r + br;
        __syncthreads();                        // S1: sh reads done, sdot ready
        if (tid < 8) {
            float iv = sdot[tid], fv = sdot[8 + tid], gv = sdot[16 + tid], ov = sdot[24 + tid];
            float cn = sigm(fv) * creg + sigm(iv) * tanhf(gv);
            float hn = sigm(ov) * tanhf(cn);
            creg = cn;
            unsigned long long pk = (((unsigned long long)(t + 1)) << 32)
                                  | (unsigned long long)__float_as_uint(hn);
            __hip_atomic_store(&hsync[t * HDIM + bid * 8 + tid], pk,
                               __ATOMIC_RELAXED, __HIP_MEMORY_SCOPE_SYSTEM);
        }
        // every thread polls its h-dim's tagged word (value IS the payload)
        unsigned long long v;
        int sp = 0;
        do {
            v = __hip_atomic_load(&hsync[t * HDIM + tid],
                                  __ATOMIC_RELAXED, __HIP_MEMORY_SCOPE_SYSTEM);
            if ((unsigned)(v >> 32) == (unsigned)(t + 1)) break;
            __builtin_amdgcn_s_sleep(1);
        } while (++sp < SPIN_CAP);
        float hv2 = __uint_as_float((unsigned)v);
        sh[tid] = hv2;                          // safe: S1 ended all sh reads of step t
        float pw = wout_r * hv2;
        pw += __shfl_down(pw, 32);
        pw += __shfl_down(pw, 16);
        pw += __shfl_down(pw, 8);
        pw += __shfl_down(pw, 4);
        pw += __shfl_down(pw, 2);
        pw += __shfl_down(pw, 1);
        if ((tid & 63) == 0) swsum[tid >> 6] = pw;
        __syncthreads();                        // S2: swsum + new sh visible
        float sval = swsum[0] + swsum[1] + swsum[2] + swsum[3] + bo;
        sinp = sval;
        if (bid == 0 && tid == 0) out[t] = sval;
    }
}

extern "C" void kernel_launch(void* const* d_in, const int* in_sizes, int n_in,
                              void* d_out, int out_size, void* d_ws, size_t ws_size,
                              hipStream_t stream) {
    const float* x       = (const float*)d_in[0];
    const int*   ei      = (const int*)d_in[1];
    const float* ew      = (const float*)d_in[2];
    const float* h       = (const float*)d_in[3];
    const float* c       = (const float*)d_in[4];
    const float* theta_x = (const float*)d_in[5];
    const float* bias_x  = (const float*)d_in[6];
    const float* theta_h = (const float*)d_in[7];
    const float* bias_h  = (const float*)d_in[8];
    const float* w_c     = (const float*)d_in[9];
    const float* b_gate  = (const float*)d_in[10];
    const float* w_ih    = (const float*)d_in[11];
    const float* w_hh    = (const float*)d_in[12];
    const float* b_ih    = (const float*)d_in[13];
    const float* b_hh    = (const float*)d_in[14];
    const float* w_out   = (const float*)d_in[15];
    const float* b_out   = (const float*)d_in[16];

    hipMemsetAsync(d_ws, 0, CTRL_BYTES, stream);
    k_mega<<<GRID, TPB, 0, stream>>>(x, ei, ew, h, c, theta_x, bias_x, theta_h, bias_h,
                                     w_c, b_gate, w_ih, w_hh, b_ih, b_hh, w_out, b_out,
                                     (float*)d_out, (char*)d_ws);
}

// Round 9
// 84.635 us; speedup vs baseline: 1.5069x; 1.0787x over previous
//
#include <hip/hip_runtime.h>
#include <math.h>

#define NN 50000
#define FD 128
#define HDIM 256
#define NE 800000
#define NBR_CAP 512
#define M_CAP 8192
#define TT 7
#define GRID 144          // 16 barrier lines x 9 arrivals; 144*8 = 1152 p-values
#define TPB 256
#define SBLK 32           // stepper blocks (first 32)
#define PPB 8             // p-values per block
#define ECHUNK 2048
#define GTH (GRID * TPB)

// ws offsets. CTRL region zeroed by the memset node each call.
#define O_BARC    0        // 16 counters x 64B stride -> 1024
#define O_GO      1024
#define O_NBRCNT  1088
#define O_MCNT    1152
#define O_HSYNC   1280     // TT*HDIM u64 -> 15616
#define O_GACC    15616    // 1024 f -> 19712
#define CTRL_BYTES 19712
#define O_DEG     19712    // NN f (zeroed in-kernel scan1)
#define O_BITMAP  219712   // 1568 u32 (zeroed in-kernel scan1)
#define O_NBRNODE 225984   // NBR_CAP i
#define O_NBRW    228032   // NBR_CAP f
#define O_MS      230080   // M_CAP i
#define O_MD      262848   // M_CAP i
#define O_MW      295616   // M_CAP f -> 328384

#define SPIN_CAP 50000000

__device__ __forceinline__ float sigm(float v) { return 1.f / (1.f + expf(-v)); }
__device__ __forceinline__ float dis_of(float dg) {
    return dg > 0.f ? rsqrtf(fmaxf(dg, 1e-20f)) : 0.f;
}
// System-scope ops execute at the LLC: always fresh (bypass L1 + per-XCD L2);
// concurrent LOADS of one line are served in parallel (unlike RMW polling).
__device__ __forceinline__ float slf(const float* p) {
    return __hip_atomic_load(p, __ATOMIC_RELAXED, __HIP_MEMORY_SCOPE_SYSTEM);
}
__device__ __forceinline__ int sli(const int* p) {
    return __hip_atomic_load(p, __ATOMIC_RELAXED, __HIP_MEMORY_SCOPE_SYSTEM);
}
__device__ __forceinline__ void ssf(float* p, float v) {
    __hip_atomic_store(p, v, __ATOMIC_RELAXED, __HIP_MEMORY_SCOPE_SYSTEM);
}
__device__ __forceinline__ void ssi(int* p, int v) {
    __hip_atomic_store(p, v, __ATOMIC_RELAXED, __HIP_MEMORY_SCOPE_SYSTEM);
}
__device__ __forceinline__ void ssu(unsigned* p, unsigned v) {
    __hip_atomic_store(p, v, __ATOMIC_RELAXED, __HIP_MEMORY_SCOPE_SYSTEM);
}

// Tree barrier: arrivals spread over 16 padded lines (9 serialized RMWs each,
// parallel across LLC channels). Root = block 0: 16 POLLER THREADS in parallel
// (not a sequential load loop), then one release go-store; others poll go.
__device__ __forceinline__ void megabar(char* ws, unsigned gen) {
    unsigned* barc = (unsigned*)(ws + O_BARC);
    unsigned* go   = (unsigned*)(ws + O_GO);
    const int tid = threadIdx.x, bid = blockIdx.x;
    __syncthreads();
    if (tid == 0)
        __hip_atomic_fetch_add(&barc[(bid & 15) * 16], 1u, __ATOMIC_RELEASE,
                               __HIP_MEMORY_SCOPE_SYSTEM);
    if (bid == 0) {
        if (tid < 16) {
            int sp = 0;
            while (__hip_atomic_load(&barc[tid * 16], __ATOMIC_ACQUIRE,
                                     __HIP_MEMORY_SCOPE_SYSTEM) < gen * (GRID / 16)) {
                __builtin_amdgcn_s_sleep(2);
                if (++sp > SPIN_CAP) break;
            }
        }
        __syncthreads();
        if (tid == 0)
            __hip_atomic_store(go, gen, __ATOMIC_RELEASE, __HIP_MEMORY_SCOPE_SYSTEM);
    } else if (tid == 0) {
        int sp = 0;
        while (__hip_atomic_load(go, __ATOMIC_ACQUIRE, __HIP_MEMORY_SCOPE_SYSTEM) < gen) {
            __builtin_amdgcn_s_sleep(2);
            if (++sp > SPIN_CAP) break;
        }
    }
    __syncthreads();
}

__global__ __launch_bounds__(TPB, 1) void k_mega(
    const float* __restrict__ x, const int* __restrict__ ei, const float* __restrict__ ew,
    const float* __restrict__ h, const float* __restrict__ c,
    const float* __restrict__ theta_x, const float* __restrict__ bias_x,
    const float* __restrict__ theta_h, const float* __restrict__ bias_h,
    const float* __restrict__ w_c, const float* __restrict__ b_gate,
    const float* __restrict__ w_ih, const float* __restrict__ w_hh,
    const float* __restrict__ b_ih, const float* __restrict__ b_hh,
    const float* __restrict__ w_out, const float* __restrict__ b_out,
    float* __restrict__ out, char* __restrict__ ws) {

    unsigned*           barc   = (unsigned*)(ws + O_BARC);
    int*                nbrCnt = (int*)(ws + O_NBRCNT);
    int*                mCnt   = (int*)(ws + O_MCNT);
    unsigned long long* hsync  = (unsigned long long*)(ws + O_HSYNC);
    float*              gacc   = (float*)(ws + O_GACC);
    float*              deg    = (float*)(ws + O_DEG);
    unsigned*           bitmap = (unsigned*)(ws + O_BITMAP);
    int*                nbrNode= (int*)(ws + O_NBRNODE);
    float*              nbrW   = (float*)(ws + O_NBRW);
    int*                mS     = (int*)(ws + O_MS);
    int*                mD     = (int*)(ws + O_MD);
    float*              mW     = (float*)(ws + O_MW);

    __shared__ int   sNode[NBR_CAP];
    __shared__ float sWl[NBR_CAP];
    __shared__ float cf1[ECHUNK], cf2[ECHUNK];
    __shared__ int   sS[ECHUNK];
    __shared__ float red1[TPB], red2[TPB];
    __shared__ float tslice[PPB];
    __shared__ __align__(16) float sh[HDIM];
    __shared__ float sc[HDIM];
    __shared__ float sdot[SBLK];
    __shared__ float swsum[4];
    __shared__ int   sCnt, sMcnt;

    const int tid = threadIdx.x, bid = blockIdx.x;
    const int gidx = bid * TPB + tid;
    const bool stepper = bid < SBLK;

    // ---- L3 warm of w_hh by the last 32 blocks (sunk, no live registers) ----
    if (bid >= GRID - 32) {
        const float4* wsrc = (const float4*)w_hh;          // 65536 float4
        int b0 = (bid - (GRID - 32)) * 2048;
        float dummy = 0.f;
        #pragma unroll
        for (int k = 0; k < 8; ++k) {
            float4 v = wsrc[b0 + k * 256 + tid];
            dummy += v.x + v.y + v.z + v.w;
        }
        asm volatile("" :: "v"(dummy));
    }

    // ================ scan1: zero deg/bitmap; collect nbr(0) ================
    for (int i = gidx; i < NN; i += GTH) ssf(&deg[i], 0.f);
    for (int i = gidx; i < 1568; i += GTH) ssu(&bitmap[i], 0u);
    for (int e0 = gidx * 4; e0 < NE; e0 += GTH * 4) {
        int4 d4 = *(const int4*)&ei[NE + e0];
        float4 w4 = *(const float4*)&ew[e0];
        int dd[4] = {d4.x, d4.y, d4.z, d4.w};
        float wv[4] = {w4.x, w4.y, w4.z, w4.w};
        #pragma unroll
        for (int k = 0; k < 4; ++k) {
            if (dd[k] == 0 && wv[k] != 0.f) {
                int s = ei[e0 + k];
                if (s != 0) {
                    int slot = atomicAdd(nbrCnt, 1);
                    if (slot < NBR_CAP) { ssi(&nbrNode[slot], s); ssf(&nbrW[slot], wv[k]); }
                }
            }
        }
    }
    megabar(ws, 1);

    // nbr list -> LDS (every block)
    if (tid == 0) sCnt = min(sli(nbrCnt), NBR_CAP);
    __syncthreads();
    const int ncnt = sCnt;
    for (int i = tid; i < ncnt; i += TPB) { sNode[i] = sli(&nbrNode[i]); sWl[i] = slf(&nbrW[i]); }
    if (bid == 0 && tid == 0) atomicOr(&bitmap[0], 1u);   // deg[0] needed
    __syncthreads();

    // ================ scan2: match edges into 2-hop set ================
    for (int e0 = gidx * 4; e0 < NE; e0 += GTH * 4) {
        int4 s4 = *(const int4*)&ei[e0];
        int4 d4 = *(const int4*)&ei[NE + e0];
        float4 w4 = *(const float4*)&ew[e0];
        int ss[4] = {s4.x, s4.y, s4.z, s4.w};
        int dd[4] = {d4.x, d4.y, d4.z, d4.w};
        float wv[4] = {w4.x, w4.y, w4.z, w4.w};
        bool m[4];
        #pragma unroll
        for (int k = 0; k < 4; ++k) m[k] = (dd[k] == 0);
        for (int j = 0; j < ncnt; ++j) {
            int nv = sNode[j];
            #pragma unroll
            for (int k = 0; k < 4; ++k) m[k] |= (dd[k] == nv);
        }
        #pragma unroll
        for (int k = 0; k < 4; ++k) {
            int s = ss[k], d = dd[k];
            float w = wv[k];
            if (s == d || w == 0.f || !m[k]) continue;
            int slot = atomicAdd(mCnt, 1);
            if (slot < M_CAP) { ssi(&mS[slot], s); ssi(&mD[slot], d); ssf(&mW[slot], w); }
            atomicOr(&bitmap[s >> 5], 1u << (s & 31));
            atomicOr(&bitmap[d >> 5], 1u << (d & 31));
        }
    }
    megabar(ws, 2);

    // ================ scan3: deg for bitmap-marked srcs ================
    for (int e0 = gidx * 4; e0 < NE; e0 += GTH * 4) {
        int4 s4 = *(const int4*)&ei[e0];
        int4 d4 = *(const int4*)&ei[NE + e0];
        float4 w4 = *(const float4*)&ew[e0];
        int ss[4] = {s4.x, s4.y, s4.z, s4.w};
        int dd[4] = {d4.x, d4.y, d4.z, d4.w};
        float wv[4] = {w4.x, w4.y, w4.z, w4.w};
        #pragma unroll
        for (int k = 0; k < 4; ++k) {
            int s = ss[k];
            if (s == dd[k] || wv[k] == 0.f) continue;
            if (bitmap[s >> 5] & (1u << (s & 31)))
                atomicAdd(&deg[s], wv[k]);
        }
    }
    megabar(ws, 3);

    // ================ graph: block-local T-slice (8 p) + gemv ================
    if (tid == 0) sMcnt = min(sli(mCnt), M_CAP);
    __syncthreads();
    const int mcnt = sMcnt;
    const float dis0 = dis_of(slf(&deg[0]));

    const int pidx = tid & 7, eg = tid >> 3;             // 32 edge-groups x 8 p
    const int p = bid * PPB + pidx;
    const bool isx = p < 3 * FD;
    const int q = isx ? p : p - 3 * FD;
    const int korder = isx ? (q / FD) : (q / HDIM);
    const int f = isx ? (q % FD) : (q % HDIM);
    const float* fbase = isx ? (x + f) : (h + f);
    const int fstride = isx ? FD : HDIM;
    const float f0 = fbase[0];

    float a1 = 0.f, a2 = 0.f;
    for (int c0i = 0; c0i < mcnt; c0i += ECHUNK) {
        int clen = min(ECHUNK, mcnt - c0i);
        for (int i = tid; i < clen; i += TPB) {          // per-edge coefs
            int sI = sli(&mS[c0i + i]), dI = sli(&mD[c0i + i]);
            float w = slf(&mW[c0i + i]);
            float disd = dis_of(slf(&deg[dI]));
            float wn = dis_of(slf(&deg[sI])) * w * disd;
            float Wd = 0.f;
            for (int j = 0; j < ncnt; ++j) Wd += (sNode[j] == dI) ? sWl[j] : 0.f;
            cf1[i] = (dI == 0) ? wn : 0.f;
            cf2[i] = wn * (dis0 * disd * Wd);
            sS[i] = sI;
        }
        __syncthreads();
        for (int i = eg; i < clen; i += 32) {            // gather-reduce
            float v = fbase[(size_t)sS[i] * fstride];
            a1 += cf1[i] * v;
            a2 += cf2[i] * v;
        }
        __syncthreads();
    }
    red1[tid] = a1; red2[tid] = a2;
    __syncthreads();
    if (tid < PPB) {
        float A1 = 0.f, A2 = 0.f;
        #pragma unroll
        for (int e = 0; e < 32; ++e) { A1 += red1[tid + 8 * e]; A2 += red2[tid + 8 * e]; }
        tslice[tid] = (korder == 0) ? f0 : ((korder == 1) ? -A1 : 2.f * A2 - f0);
    }
    __syncthreads();

    {   // gemv over this block's 8 p-rows; thread owns output o = tid
        float g0 = 0.f, g1 = 0.f, g2v = 0.f, g3 = 0.f;
        #pragma unroll
        for (int pp = 0; pp < PPB; ++pp) {
            int p2 = bid * PPB + pp;
            float tv = tslice[pp];
            bool ix = p2 < 3 * FD;
            int qq = ix ? p2 : p2 - 3 * FD;
            const float* bb = ix ? (theta_x + (size_t)qq * HDIM)
                                 : (theta_h + (size_t)qq * HDIM);
            size_t gs = ix ? (size_t)(3 * FD) * HDIM : (size_t)(3 * HDIM) * HDIM;
            g0  += tv * bb[tid];
            g1  += tv * bb[gs + tid];
            g2v += tv * bb[2 * gs + tid];
            g3  += tv * bb[3 * gs + tid];
        }
        atomicAdd(&gacc[0 * HDIM + tid], g0);
        atomicAdd(&gacc[1 * HDIM + tid], g1);
        atomicAdd(&gacc[2 * HDIM + tid], g2v);
        atomicAdd(&gacc[3 * HDIM + tid], g3);
    }

    // B4: non-steppers arrive and exit; steppers run the full tree barrier.
    __syncthreads();
    if (!stepper) {
        if (tid == 0)
            __hip_atomic_fetch_add(&barc[(bid & 15) * 16], 1u, __ATOMIC_RELEASE,
                                   __HIP_MEMORY_SCOPE_SYSTEM);
        return;
    }
    megabar(ws, 4);

    // ---- NOW load step weights (live range = steps only -> no spill; L3-warm) ----
    const int rl = tid >> 3, seg = tid & 7;
    const int grow = (rl >> 3) * HDIM + bid * 8 + (rl & 7);
    float4 wreg[8];
    #pragma unroll
    for (int k = 0; k < 8; ++k)
        wreg[k] = *(const float4*)&w_hh[(size_t)grow * HDIM + seg * 32 + k * 4];
    const float wih_r = w_ih[grow];
    const float br    = b_ih[grow] + b_hh[grow];
    const float bo    = b_out[0];
    const float wout_r = w_out[tid];

    // ================ gates (redundant per stepper block) ================
    {
        const int o = tid;
        float g0 = slf(&gacc[0 * HDIM + o]) + bias_x[0 * HDIM + o] + bias_h[0 * HDIM + o];
        float g1 = slf(&gacc[1 * HDIM + o]) + bias_x[1 * HDIM + o] + bias_h[1 * HDIM + o];
        float g2 = slf(&gacc[2 * HDIM + o]) + bias_x[2 * HDIM + o] + bias_h[2 * HDIM + o];
        float g3 = slf(&gacc[3 * HDIM + o]) + bias_x[3 * HDIM + o] + bias_h[3 * HDIM + o];
        float c0 = c[o];
        float I  = sigm(g0 + w_c[0 * HDIM + o] * c0 + b_gate[0 * HDIM + o]);
        float Fg = sigm(g1 + w_c[1 * HDIM + o] * c0 + b_gate[1 * HDIM + o]);
        float Cn = Fg * c0 + I * tanhf(g2 + b_gate[2 * HDIM + o]);
        float O  = sigm(g3 + w_c[2 * HDIM + o] * Cn + b_gate[3 * HDIM + o]);
        sh[o] = O * tanhf(Cn);
        sc[o] = Cn;
    }
    __syncthreads();
    float creg = (tid < 8) ? sc[bid * 8 + tid] : 0.f;
    float sinp = x[FD - 1];

    // ====== 7 LSTM steps: one tagged u64 store per h-value, consumers poll it ======
    for (int t = 0; t < TT; ++t) {
        float acc = 0.f;
        const float* shh = &sh[seg * 32];
        #pragma unroll
        for (int k = 0; k < 8; ++k) {
            float4 hv = *(const float4*)&shh[k * 4];
            acc += hv.x * wreg[k].x + hv.y * wreg[k].y + hv.z * wreg[k].z + hv.w * wreg[k].w;
        }
        acc += __shfl_down(acc, 4);
        acc += __shfl_down(acc, 2);
        acc += __shfl_down(acc, 1);
        if (seg == 0) sdot[rl] = acc + sinp * wih_r + br;
        __syncthreads();                        // S1: sh reads done, sdot ready
        if (tid < 8) {
            float iv = sdot[tid], fv = sdot[8 + tid], gv = sdot[16 + tid], ov = sdot[24 + tid];
            float cn = sigm(fv) * creg + sigm(iv) * tanhf(gv);
            float hn = sigm(ov) * tanhf(cn);
            creg = cn;
            unsigned long long pk = (((unsigned long long)(t + 1)) << 32)
                                  | (unsigned long long)__float_as_uint(hn);
            __hip_atomic_store(&hsync[t * HDIM + bid * 8 + tid], pk,
                               __ATOMIC_RELAXED, __HIP_MEMORY_SCOPE_SYSTEM);
        }
        // every thread polls its h-dim's tagged word (value IS the payload)
        unsigned long long v;
        int sp = 0;
        do {
            v = __hip_atomic_load(&hsync[t * HDIM + tid],
                                  __ATOMIC_RELAXED, __HIP_MEMORY_SCOPE_SYSTEM);
            if ((unsigned)(v >> 32) == (unsigned)(t + 1)) break;
            __builtin_amdgcn_s_sleep(1);
        } while (++sp < SPIN_CAP);
        float hv2 = __uint_as_float((unsigned)v);
        sh[tid] = hv2;                          // safe: S1 ended all sh reads of step t
        float pw = wout_r * hv2;
        pw += __shfl_down(pw, 32);
        pw += __shfl_down(pw, 16);
        pw += __shfl_down(pw, 8);
        pw += __shfl_down(pw, 4);
        pw += __shfl_down(pw, 2);
        pw += __shfl_down(pw, 1);
        if ((tid & 63) == 0) swsum[tid >> 6] = pw;
        __syncthreads();                        // S2: swsum + new sh visible
        float sval = swsum[0] + swsum[1] + swsum[2] + swsum[3] + bo;
        sinp = sval;
        if (bid == 0 && tid == 0) out[t] = sval;
    }
}

extern "C" void kernel_launch(void* const* d_in, const int* in_sizes, int n_in,
                              void* d_out, int out_size, void* d_ws, size_t ws_size,
                              hipStream_t stream) {
    const float* x       = (const float*)d_in[0];
    const int*   ei      = (const int*)d_in[1];
    const float* ew      = (const float*)d_in[2];
    const float* h       = (const float*)d_in[3];
    const float* c       = (const float*)d_in[4];
    const float* theta_x = (const float*)d_in[5];
    const float* bias_x  = (const float*)d_in[6];
    const float* theta_h = (const float*)d_in[7];
    const float* bias_h  = (const float*)d_in[8];
    const float* w_c     = (const float*)d_in[9];
    const float* b_gate  = (const float*)d_in[10];
    const float* w_ih    = (const float*)d_in[11];
    const float* w_hh    = (const float*)d_in[12];
    const float* b_ih    = (const float*)d_in[13];
    const float* b_hh    = (const float*)d_in[14];
    const float* w_out   = (const float*)d_in[15];
    const float* b_out   = (const float*)d_in[16];

    hipMemsetAsync(d_ws, 0, CTRL_BYTES, stream);
    k_mega<<<GRID, TPB, 0, stream>>>(x, ei, ew, h, c, theta_x, bias_x, theta_h, bias_h,
                                     w_c, b_gate, w_ih, w_hh, b_ih, b_hh, w_out, b_out,
                                     (float*)d_out, (char*)d_ws);
}

// Round 10
// 73.493 us; speedup vs baseline: 1.7354x; 1.1516x over previous
//
#include <hip/hip_runtime.h>
#include <math.h>

#define NN 50000
#define FD 128
#define HDIM 256
#define NE 800000
#define NBR_CAP 512
#define M_CAP 8192
#define TT 7
#define TAILB 32
#define TPB 256
#define PSLICE 36            // 32 blocks x 36 = 1152 p-values
#define ECHUNK 2048
#define SPIN_CAP 50000000

// ws offsets
#define O_NBRCNT   0         // zeroed by the 64 B memset node
#define O_BARC     64        // 16 lines x 64 B -> 1088 (zeroed by k_nbr)
#define O_GO       1088
#define O_MCNT     1152
#define O_HSYNC    1216      // TT*HDIM u64 = 14336 -> 15552
#define O_GACC     15552     // 1024 f -> 19648
#define O_ZERO_END 19648     // k_nbr zeroes [64, 19648)
#define O_DEG      19648     // NN f -> 219648 (zeroed by k_nbr)
#define O_BITMAP   219648    // 1568 u32 -> 225920 (zeroed by k_nbr)
#define O_NBRNODE  225920    // NBR_CAP i
#define O_NBRW     227968    // NBR_CAP f
#define O_MS       230016    // M_CAP i
#define O_MD       262784    // M_CAP i
#define O_MW       295552    // M_CAP f -> 328320

__device__ __forceinline__ float sigm(float v) { return 1.f / (1.f + expf(-v)); }
__device__ __forceinline__ float dis_of(float dg) {
    return dg > 0.f ? rsqrtf(fmaxf(dg, 1e-20f)) : 0.f;
}
__device__ __forceinline__ float slf(const float* p) {
    return __hip_atomic_load(p, __ATOMIC_RELAXED, __HIP_MEMORY_SCOPE_SYSTEM);
}

// Scan 1: zero deg/bitmap/ctrl; collect nbr(0); warm theta+w_hh into L3.
__global__ void k_nbr(const int* __restrict__ ei, const float* __restrict__ ew,
                      const float* __restrict__ theta_x, const float* __restrict__ theta_h,
                      const float* __restrict__ w_hh, char* __restrict__ ws) {
    float*    deg    = (float*)(ws + O_DEG);
    unsigned* bitmap = (unsigned*)(ws + O_BITMAP);
    int*      nbrCnt = (int*)(ws + O_NBRCNT);
    int*      nbrNode= (int*)(ws + O_NBRNODE);
    float*    nbrW   = (float*)(ws + O_NBRW);

    int gid = blockIdx.x * blockDim.x + threadIdx.x;
    if (gid < NN) deg[gid] = 0.f;
    if (gid < 1568) bitmap[gid] = 0u;
    if (gid < (O_ZERO_END - O_BARC) / 4) ((unsigned*)(ws + O_BARC))[gid] = 0u;

    // L3 warm: blocks 600+ stream theta_x|theta_h|w_hh (5.75 MB total) into sinks.
    if (blockIdx.x >= 600) {
        const int wb = blockIdx.x - 600, NWB = 182;
        const float4* tx4 = (const float4*)theta_x;   //  98304 f4
        const float4* th4 = (const float4*)theta_h;   // 196608 f4
        const float4* wh4 = (const float4*)w_hh;      //  65536 f4
        float acc = 0.f;
        for (int idx = wb * 256 + threadIdx.x; idx < 360448; idx += NWB * 256) {
            float4 v;
            if (idx < 98304)       v = tx4[idx];
            else if (idx < 294912) v = th4[idx - 98304];
            else                   v = wh4[idx - 294912];
            acc += v.x + v.y + v.z + v.w;
        }
        asm volatile("" :: "v"(acc));
    }

    int e0 = gid * 4;
    if (e0 >= NE) return;
    int4 d4 = *(const int4*)&ei[NE + e0];
    float4 w4 = *(const float4*)&ew[e0];
    int dd[4] = {d4.x, d4.y, d4.z, d4.w};
    float wv[4] = {w4.x, w4.y, w4.z, w4.w};
    #pragma unroll
    for (int k = 0; k < 4; ++k) {
        if (dd[k] == 0 && wv[k] != 0.f) {
            int s = ei[e0 + k];
            if (s != 0) {
                int slot = atomicAdd(nbrCnt, 1);
                if (slot < NBR_CAP) { nbrNode[slot] = s; nbrW[slot] = wv[k]; }
            }
        }
    }
}

// Scan 2: match edges with d==0 or d in nbr(0); record (s,d,w); mark needed nodes.
__global__ void k_match(const int* __restrict__ ei, const float* __restrict__ ew,
                        char* __restrict__ ws) {
    const int* nbrCnt = (const int*)(ws + O_NBRCNT);
    const int* nbrNode= (const int*)(ws + O_NBRNODE);
    int*      mCnt   = (int*)(ws + O_MCNT);
    int*      mS     = (int*)(ws + O_MS);
    int*      mD     = (int*)(ws + O_MD);
    float*    mW     = (float*)(ws + O_MW);
    unsigned* bitmap = (unsigned*)(ws + O_BITMAP);

    __shared__ int sNode[NBR_CAP];
    __shared__ int sCnt;
    if (threadIdx.x == 0) sCnt = min(*nbrCnt, NBR_CAP);
    __syncthreads();
    int cnt = sCnt;
    for (int i = threadIdx.x; i < cnt; i += blockDim.x) sNode[i] = nbrNode[i];
    __syncthreads();
    if (blockIdx.x == 0 && threadIdx.x == 0) atomicOr(&bitmap[0], 1u);

    int i = blockIdx.x * blockDim.x + threadIdx.x;
    int e0 = i * 4;
    if (e0 >= NE) return;
    int4 s4 = *(const int4*)&ei[e0];
    int4 d4 = *(const int4*)&ei[NE + e0];
    float4 w4 = *(const float4*)&ew[e0];
    int ss[4] = {s4.x, s4.y, s4.z, s4.w};
    int dd[4] = {d4.x, d4.y, d4.z, d4.w};
    float wv[4] = {w4.x, w4.y, w4.z, w4.w};
    bool m[4];
    #pragma unroll
    for (int k = 0; k < 4; ++k) m[k] = (dd[k] == 0);
    for (int j = 0; j < cnt; ++j) {
        int nv = sNode[j];
        #pragma unroll
        for (int k = 0; k < 4; ++k) m[k] |= (dd[k] == nv);
    }
    #pragma unroll
    for (int k = 0; k < 4; ++k) {
        int s = ss[k], d = dd[k];
        float w = wv[k];
        if (s == d || w == 0.f || !m[k]) continue;
        int slot = atomicAdd(mCnt, 1);
        if (slot < M_CAP) { mS[slot] = s; mD[slot] = d; mW[slot] = w; }
        atomicOr(&bitmap[s >> 5], 1u << (s & 31));
        atomicOr(&bitmap[d >> 5], 1u << (d & 31));
    }
}

// Scan 3: deg[s] += w only for bitmap-marked srcs.
__global__ void k_deg(const int* __restrict__ ei, const float* __restrict__ ew,
                      char* __restrict__ ws) {
    const unsigned* bitmap = (const unsigned*)(ws + O_BITMAP);
    float* deg = (float*)(ws + O_DEG);
    int i = blockIdx.x * blockDim.x + threadIdx.x;
    int e0 = i * 4;
    if (e0 >= NE) return;
    int4 s4 = *(const int4*)&ei[e0];
    int4 d4 = *(const int4*)&ei[NE + e0];
    float4 w4 = *(const float4*)&ew[e0];
    int ss[4] = {s4.x, s4.y, s4.z, s4.w};
    int dd[4] = {d4.x, d4.y, d4.z, d4.w};
    float wv[4] = {w4.x, w4.y, w4.z, w4.w};
    #pragma unroll
    for (int k = 0; k < 4; ++k) {
        int s = ss[k];
        if (s == dd[k] || wv[k] == 0.f) continue;
        if (bitmap[s >> 5] & (1u << (s & 31)))
            atomicAdd(&deg[s], wv[k]);
    }
}

// Tail: block-local T-slice -> gemv -> tree barrier -> gates -> 7 steps.
// 32 blocks x 256 threads. Block b: p-slice [b*36, b*36+36), gate rows
// {g*256 + b*8 + k} in VGPRs (loaded post-barrier), h-outputs [b*8, b*8+8).
__global__ __launch_bounds__(TPB) void k_tail(
    const float* __restrict__ x, const float* __restrict__ h, const float* __restrict__ c,
    const float* __restrict__ theta_x, const float* __restrict__ bias_x,
    const float* __restrict__ theta_h, const float* __restrict__ bias_h,
    const float* __restrict__ w_c, const float* __restrict__ b_gate,
    const float* __restrict__ w_ih, const float* __restrict__ w_hh,
    const float* __restrict__ b_ih, const float* __restrict__ b_hh,
    const float* __restrict__ w_out, const float* __restrict__ b_out,
    float* __restrict__ out, char* __restrict__ ws) {

    const float*        deg    = (const float*)(ws + O_DEG);
    const int*          nbrCnt = (const int*)(ws + O_NBRCNT);
    const int*          mCnt   = (const int*)(ws + O_MCNT);
    unsigned*           barc   = (unsigned*)(ws + O_BARC);
    unsigned*           go     = (unsigned*)(ws + O_GO);
    unsigned long long* hsync  = (unsigned long long*)(ws + O_HSYNC);
    float*              gacc   = (float*)(ws + O_GACC);
    const int*          nbrNode= (const int*)(ws + O_NBRNODE);
    const float*        nbrW   = (const float*)(ws + O_NBRW);
    const int*          mS     = (const int*)(ws + O_MS);
    const int*          mD     = (const int*)(ws + O_MD);
    const float*        mW     = (const float*)(ws + O_MW);

    __shared__ int   sNode[NBR_CAP];
    __shared__ float sWl[NBR_CAP];
    __shared__ float cf1[ECHUNK], cf2[ECHUNK];
    __shared__ int   sS[ECHUNK];
    __shared__ float tp1[7][PSLICE], tp2[7][PSLICE];
    __shared__ float tslice[PSLICE];
    __shared__ __align__(16) float sh[HDIM];
    __shared__ float sc[HDIM];
    __shared__ float sdot[32];
    __shared__ float swsum[4];
    __shared__ int   sCnt, sMcnt;

    const int tid = threadIdx.x, bid = blockIdx.x;

    if (tid == 0) { sCnt = min(*nbrCnt, NBR_CAP); sMcnt = min(*mCnt, M_CAP); }
    __syncthreads();
    const int ncnt = sCnt, mcnt = sMcnt;
    for (int i = tid; i < ncnt; i += TPB) { sNode[i] = nbrNode[i]; sWl[i] = nbrW[i]; }
    __syncthreads();

    // ---- phase A: block-local T-slice (all plain cached loads) ----
    const float dis0 = dis_of(deg[0]);
    const int pl = tid % PSLICE, gr = tid / PSLICE;       // 7 full edge-groups
    const int p = bid * PSLICE + pl;
    const bool isx = p < 3 * FD;
    const int q = isx ? p : p - 3 * FD;
    const int korder = isx ? (q / FD) : (q / HDIM);
    const int f = isx ? (q % FD) : (q % HDIM);
    const float* fbase = isx ? (x + f) : (h + f);
    const int fstride = isx ? FD : HDIM;
    const float f0 = fbase[0];

    float a1 = 0.f, a2 = 0.f;
    for (int c0i = 0; c0i < mcnt; c0i += ECHUNK) {
        int clen = min(ECHUNK, mcnt - c0i);
        for (int i = tid; i < clen; i += TPB) {           // per-edge coefs
            int sI = mS[c0i + i], dI = mD[c0i + i];
            float w = mW[c0i + i];
            float disd = dis_of(deg[dI]);
            float wn = dis_of(deg[sI]) * w * disd;
            float Wd = 0.f;
            for (int j = 0; j < ncnt; ++j) Wd += (sNode[j] == dI) ? sWl[j] : 0.f;
            cf1[i] = (dI == 0) ? wn : 0.f;
            cf2[i] = wn * (dis0 * disd * Wd);
            sS[i] = sI;
        }
        __syncthreads();
        if (gr < 7) {
            for (int i = gr; i < clen; i += 7) {          // gather-reduce
                float v = fbase[(size_t)sS[i] * fstride];
                a1 += cf1[i] * v;
                a2 += cf2[i] * v;
            }
        }
        __syncthreads();
    }
    if (gr < 7) { tp1[gr][pl] = a1; tp2[gr][pl] = a2; }
    __syncthreads();
    if (tid < PSLICE) {
        float A1 = 0.f, A2 = 0.f;
        #pragma unroll
        for (int g2 = 0; g2 < 7; ++g2) { A1 += tp1[g2][tid]; A2 += tp2[g2][tid]; }
        tslice[tid] = (korder == 0) ? f0 : ((korder == 1) ? -A1 : 2.f * A2 - f0);
    }
    __syncthreads();

    // ---- phase B: gemv over this block's 36 p-rows (theta L3-warm) ----
    {
        const int oq = tid & 63, pseg = tid >> 6;
        const int p0 = bid * PSLICE + pseg * 9;
        float4 a0 = {0,0,0,0}, b1 = {0,0,0,0}, a2v = {0,0,0,0}, a3 = {0,0,0,0};
        #pragma unroll
        for (int pp = 0; pp < 9; ++pp) {
            int p2 = p0 + pp;
            bool ix = p2 < 3 * FD;
            int qq = ix ? p2 : p2 - 3 * FD;
            float tv = tslice[pseg * 9 + pp];
            const float* bb = ix ? (theta_x + (size_t)qq * HDIM)
                                 : (theta_h + (size_t)qq * HDIM);
            size_t gs = ix ? (size_t)(3 * FD) * HDIM : (size_t)(3 * HDIM) * HDIM;
            float4 v0 = *(const float4*)&bb[oq * 4];
            float4 v1 = *(const float4*)&bb[gs + oq * 4];
            float4 v2 = *(const float4*)&bb[2 * gs + oq * 4];
            float4 v3 = *(const float4*)&bb[3 * gs + oq * 4];
            a0.x += tv * v0.x; a0.y += tv * v0.y; a0.z += tv * v0.z; a0.w += tv * v0.w;
            b1.x += tv * v1.x; b1.y += tv * v1.y; b1.z += tv * v1.z; b1.w += tv * v1.w;
            a2v.x += tv * v2.x; a2v.y += tv * v2.y; a2v.z += tv * v2.z; a2v.w += tv * v2.w;
            a3.x += tv * v3.x; a3.y += tv * v3.y; a3.z += tv * v3.z; a3.w += tv * v3.w;
        }
        int ob = oq * 4;
        atomicAdd(&gacc[0 * HDIM + ob + 0], a0.x); atomicAdd(&gacc[0 * HDIM + ob + 1], a0.y);
        atomicAdd(&gacc[0 * HDIM + ob + 2], a0.z); atomicAdd(&gacc[0 * HDIM + ob + 3], a0.w);
        atomicAdd(&gacc[1 * HDIM + ob + 0], b1.x); atomicAdd(&gacc[1 * HDIM + ob + 1], b1.y);
        atomicAdd(&gacc[1 * HDIM + ob + 2], b1.z); atomicAdd(&gacc[1 * HDIM + ob + 3], b1.w);
        atomicAdd(&gacc[2 * HDIM + ob + 0], a2v.x); atomicAdd(&gacc[2 * HDIM + ob + 1], a2v.y);
        atomicAdd(&gacc[2 * HDIM + ob + 2], a2v.z); atomicAdd(&gacc[2 * HDIM + ob + 3], a2v.w);
        atomicAdd(&gacc[3 * HDIM + ob + 0], a3.x); atomicAdd(&gacc[3 * HDIM + ob + 1], a3.y);
        atomicAdd(&gacc[3 * HDIM + ob + 2], a3.z); atomicAdd(&gacc[3 * HDIM + ob + 3], a3.w);
    }

    // ---- tree barrier: 16 lines x 2 arrivals; root block broadcasts go ----
    __syncthreads();
    if (tid == 0)
        __hip_atomic_fetch_add(&barc[(bid & 15) * 16], 1u, __ATOMIC_RELEASE,
                               __HIP_MEMORY_SCOPE_SYSTEM);
    if (bid == 0) {
        if (tid < 16) {
            int sp = 0;
            while (__hip_atomic_load(&barc[tid * 16], __ATOMIC_ACQUIRE,
                                     __HIP_MEMORY_SCOPE_SYSTEM) < TAILB / 16u) {
                __builtin_amdgcn_s_sleep(2);
                if (++sp > SPIN_CAP) break;
            }
        }
        __syncthreads();
        if (tid == 0)
            __hip_atomic_store(go, 1u, __ATOMIC_RELEASE, __HIP_MEMORY_SCOPE_SYSTEM);
    } else if (tid == 0) {
        int sp = 0;
        while (__hip_atomic_load(go, __ATOMIC_ACQUIRE, __HIP_MEMORY_SCOPE_SYSTEM) < 1u) {
            __builtin_amdgcn_s_sleep(2);
            if (++sp > SPIN_CAP) break;
        }
    }
    __syncthreads();

    // ---- step weights: short live range, L3-warm ----
    const int rl = tid >> 3, seg = tid & 7;
    const int grow = (rl >> 3) * HDIM + bid * 8 + (rl & 7);
    float4 wreg[8];
    #pragma unroll
    for (int k = 0; k < 8; ++k)
        wreg[k] = *(const float4*)&w_hh[(size_t)grow * HDIM + seg * 32 + k * 4];
    const float wih_r = w_ih[grow];
    const float br    = b_ih[grow] + b_hh[grow];
    const float bo    = b_out[0];
    const float wout_r = w_out[tid];

    // ---- gates (redundant per block): gacc via system loads ----
    {
        const int o = tid;
        float g0 = slf(&gacc[0 * HDIM + o]) + bias_x[0 * HDIM + o] + bias_h[0 * HDIM + o];
        float g1 = slf(&gacc[1 * HDIM + o]) + bias_x[1 * HDIM + o] + bias_h[1 * HDIM + o];
        float g2 = slf(&gacc[2 * HDIM + o]) + bias_x[2 * HDIM + o] + bias_h[2 * HDIM + o];
        float g3 = slf(&gacc[3 * HDIM + o]) + bias_x[3 * HDIM + o] + bias_h[3 * HDIM + o];
        float c0 = c[o];
        float I  = sigm(g0 + w_c[0 * HDIM + o] * c0 + b_gate[0 * HDIM + o]);
        float Fg = sigm(g1 + w_c[1 * HDIM + o] * c0 + b_gate[1 * HDIM + o]);
        float Cn = Fg * c0 + I * tanhf(g2 + b_gate[2 * HDIM + o]);
        float O  = sigm(g3 + w_c[2 * HDIM + o] * Cn + b_gate[3 * HDIM + o]);
        sh[o] = O * tanhf(Cn);
        sc[o] = Cn;
    }
    __syncthreads();
    float creg = (tid < 8) ? sc[bid * 8 + tid] : 0.f;
    float sinp = x[FD - 1];

    // ---- 7 steps: tagged-u64 h exchange, wave-0-only polling ----
    for (int t = 0; t < TT; ++t) {
        float acc = 0.f;
        const float* shh = &sh[seg * 32];
        #pragma unroll
        for (int k = 0; k < 8; ++k) {
            float4 hv = *(const float4*)&shh[k * 4];
            acc += hv.x * wreg[k].x + hv.y * wreg[k].y + hv.z * wreg[k].z + hv.w * wreg[k].w;
        }
        acc += __shfl_down(acc, 4);
        acc += __shfl_down(acc, 2);
        acc += __shfl_down(acc, 1);
        if (seg == 0) sdot[rl] = acc + sinp * wih_r + br;
        __syncthreads();                        // S1: sh reads done, sdot ready
        if (tid < 8) {
            float iv = sdot[tid], fv = sdot[8 + tid], gv = sdot[16 + tid], ov = sdot[24 + tid];
            float cn = sigm(fv) * creg + sigm(iv) * tanhf(gv);
            float hn = sigm(ov) * tanhf(cn);
            creg = cn;
            unsigned long long pk = (((unsigned long long)(t + 1)) << 32)
                                  | (unsigned long long)__float_as_uint(hn);
            __hip_atomic_store(&hsync[t * HDIM + bid * 8 + tid], pk,
                               __ATOMIC_RELAXED, __HIP_MEMORY_SCOPE_SYSTEM);
        }
        if (tid < 64) {                         // wave 0 polls 4 tagged words each
            #pragma unroll
            for (int j = 0; j < 4; ++j) {
                unsigned long long v;
                int sp = 0;
                do {
                    v = __hip_atomic_load(&hsync[t * HDIM + tid * 4 + j],
                                          __ATOMIC_RELAXED, __HIP_MEMORY_SCOPE_SYSTEM);
                    if ((unsigned)(v >> 32) == (unsigned)(t + 1)) break;
                    __builtin_amdgcn_s_sleep(1);
                } while (++sp < SPIN_CAP);
                sh[tid * 4 + j] = __uint_as_float((unsigned)v);
            }
        }
        __syncthreads();                        // S2: new h visible to all
        float pw = wout_r * sh[tid];
        pw += __shfl_down(pw, 32);
        pw += __shfl_down(pw, 16);
        pw += __shfl_down(pw, 8);
        pw += __shfl_down(pw, 4);
        pw += __shfl_down(pw, 2);
        pw += __shfl_down(pw, 1);
        if ((tid & 63) == 0) swsum[tid >> 6] = pw;
        __syncthreads();                        // S3: swsum ready
        float sval = swsum[0] + swsum[1] + swsum[2] + swsum[3] + bo;
        sinp = sval;
        if (bid == 0 && tid == 0) out[t] = sval;
    }
}

extern "C" void kernel_launch(void* const* d_in, const int* in_sizes, int n_in,
                              void* d_out, int out_size, void* d_ws, size_t ws_size,
                              hipStream_t stream) {
    const float* x       = (const float*)d_in[0];
    const int*   ei      = (const int*)d_in[1];
    const float* ew      = (const float*)d_in[2];
    const float* h       = (const float*)d_in[3];
    const float* c       = (const float*)d_in[4];
    const float* theta_x = (const float*)d_in[5];
    const float* bias_x  = (const float*)d_in[6];
    const float* theta_h = (const float*)d_in[7];
    const float* bias_h  = (const float*)d_in[8];
    const float* w_c     = (const float*)d_in[9];
    const float* b_gate  = (const float*)d_in[10];
    const float* w_ih    = (const float*)d_in[11];
    const float* w_hh    = (const float*)d_in[12];
    const float* b_ih    = (const float*)d_in[13];
    const float* b_hh    = (const float*)d_in[14];
    const float* w_out   = (const float*)d_in[15];
    const float* b_out   = (const float*)d_in[16];
    char* ws = (char*)d_ws;

    hipMemsetAsync(ws, 0, 64, stream);          // nbrCnt only; rest zeroed by k_nbr

    int eb4 = (NE / 4 + TPB - 1) / TPB;         // 782 blocks
    k_nbr<<<eb4, TPB, 0, stream>>>(ei, ew, theta_x, theta_h, w_hh, ws);
    k_match<<<eb4, TPB, 0, stream>>>(ei, ew, ws);
    k_deg<<<eb4, TPB, 0, stream>>>(ei, ew, ws);
    k_tail<<<TAILB, TPB, 0, stream>>>(x, h, c, theta_x, bias_x, theta_h, bias_h,
                                      w_c, b_gate, w_ih, w_hh, b_ih, b_hh, w_out, b_out,
                                      (float*)d_out, ws);
}